// Round 1
// baseline (15204.251 us; speedup 1.0000x reference)
//
#include <hip/hip_runtime.h>
#include <hip/hip_bf16.h>
#include <math.h>

#define B_    4
#define SEQ_  1024
#define E_    512
#define H_    8
#define DH_   64
#define NHYP_ 6
#define HID_  2048
#define NC_   6
#define ENC_  6

static __device__ __forceinline__ float wave_rsum(float v){
#pragma unroll
  for(int o=32;o;o>>=1) v += __shfl_down(v,o,64);
  return v;
}
static __device__ __forceinline__ float wave_rmax(float v){
#pragma unroll
  for(int o=32;o;o>>=1) v = fmaxf(v,__shfl_down(v,o,64));
  return v;
}

// x[b,s,:] = emb[idx[b,s],:] + pos_encoding(s,:)
__global__ void embed_pe_kernel(const int* __restrict__ inp, const float* __restrict__ emb,
                                float* __restrict__ x){
  int row = blockIdx.x;            // b*SEQ + s
  int s = row & (SEQ_-1);
  int idx = inp[row];
  const float* er = emb + (size_t)idx*E_;
  float* xr = x + (size_t)row*E_;
  for(int c=threadIdx.x;c<E_;c+=blockDim.x){
    int i = c>>1;
    // div_i = exp(-(2i)*ln(10000)/512) = exp(-i*0.035977892)
    float div = expf(-(float)i * 0.0359778920780319646f);
    float ang = (float)s * div;
    float pe = (c&1) ? cosf(ang) : sinf(ang);
    xr[c] = er[c] + pe;
  }
}

// C[M,N] = A[M,K]@B[K,N] + bias, EPI: 0=bias, 1=bias+relu, 2=bias+residual
template<int EPI>
__global__ void gemm_f32(const float* __restrict__ A, const float* __restrict__ Bm,
                         const float* __restrict__ bias, const float* __restrict__ res,
                         float* __restrict__ C, int M, int N, int K){
  __shared__ float As[16][65];   // As[k][m]
  __shared__ float Bs[16][65];   // Bs[k][n]
  int tid = threadIdx.x;
  int tx = tid & 15, ty = tid >> 4;
  int bn = blockIdx.x * 64, bm = blockIdx.y * 64;
  float acc[4][4] = {};
  for(int k0=0;k0<K;k0+=16){
    {
      int kk = tid & 15, m = tid >> 4;
#pragma unroll
      for(int p=0;p<4;++p)
        As[kk][m + p*16] = A[(size_t)(bm + m + p*16)*K + k0 + kk];
      int n = tid & 63, k2 = tid >> 6;
#pragma unroll
      for(int p=0;p<4;++p)
        Bs[k2 + p*4][n] = Bm[(size_t)(k0 + k2 + p*4)*N + bn + n];
    }
    __syncthreads();
#pragma unroll
    for(int kk=0;kk<16;++kk){
      float a[4], bv[4];
#pragma unroll
      for(int i=0;i<4;++i) a[i] = As[kk][ty + 16*i];
#pragma unroll
      for(int j=0;j<4;++j) bv[j] = Bs[kk][tx + 16*j];
#pragma unroll
      for(int i=0;i<4;++i)
#pragma unroll
        for(int j=0;j<4;++j) acc[i][j] += a[i]*bv[j];
    }
    __syncthreads();
  }
#pragma unroll
  for(int i=0;i<4;++i){
    int r = bm + ty + 16*i;
#pragma unroll
    for(int j=0;j<4;++j){
      int c = bn + tx + 16*j;
      float vv = acc[i][j] + bias[c];
      if(EPI==1) vv = fmaxf(vv, 0.0f);
      if(EPI==2) vv += res[(size_t)r*N + c];
      C[(size_t)r*N + c] = vv;
    }
  }
}

// buckets[b,h,n] from q[b,n,h,:]: proj = [q,1]@hyper, bits=(proj>=0), binary encode
__global__ void bucket_kernel(const float* __restrict__ q, const float* __restrict__ hyper,
                              int* __restrict__ buckets){
  int t = blockIdx.x*256 + threadIdx.x;
  if(t >= B_*SEQ_*H_) return;
  int h = t & (H_-1);
  int n = (t >> 3) & (SEQ_-1);
  int b = t >> 13;
  const float* qr = q + ((size_t)(b*SEQ_ + n))*E_ + h*DH_;
  float pr[NHYP_];
#pragma unroll
  for(int y=0;y<NHYP_;++y) pr[y] = hyper[DH_*NHYP_ + y];   // bias-1 row
  for(int d=0;d<DH_;++d){
    float qd = qr[d];
#pragma unroll
    for(int y=0;y<NHYP_;++y) pr[y] += qd * hyper[d*NHYP_ + y];
  }
  int bk = 0;
#pragma unroll
  for(int y=0;y<NHYP_;++y) bk |= (pr[y] >= 0.0f) ? (1<<y) : 0;
  buckets[(b*H_ + h)*SEQ_ + n] = bk;
}

// one block per (b,h,row): logits -> softmax -> out = attn @ v
__global__ void attn_kernel(const float* __restrict__ q, const float* __restrict__ v,
                            const int* __restrict__ buckets, float* __restrict__ outp){
  int bid = blockIdx.x;
  int row = bid & (SEQ_-1);
  int bh  = bid >> 10;          // b*H + h
  int h = bh & (H_-1);
  int b = bh >> 3;
  int tid = threadIdx.x;
  __shared__ float p[SEQ_];
  __shared__ float qrow[DH_];
  __shared__ float sred[8];
  __shared__ float ored[4][DH_];
  const float* qbase = q + (size_t)b*SEQ_*E_ + h*DH_;
  if(tid < DH_) qrow[tid] = qbase[(size_t)row*E_ + tid];
  const int* brow = buckets + bh*SEQ_;
  int myb = brow[row];
  __syncthreads();
  const float invsq = 0.04419417382415922f;   // 1/sqrt(512)
  float lmax = -1e30f;
  for(int j=tid;j<SEQ_;j+=256){
    const float4* qj = (const float4*)(qbase + (size_t)j*E_);
    float dot = 0.f;
#pragma unroll
    for(int d4=0; d4<DH_/4; ++d4){
      float4 qv = qj[d4];
      dot += qv.x*qrow[d4*4+0] + qv.y*qrow[d4*4+1] + qv.z*qrow[d4*4+2] + qv.w*qrow[d4*4+3];
    }
    float cnt = (brow[j]==myb) ? 63.0f : 62.0f;
    float logit = dot * invsq * cnt;
    p[j] = logit;
    lmax = fmaxf(lmax, logit);
  }
  float wm = wave_rmax(lmax);
  int w = tid>>6, lane = tid&63;
  if(lane==0) sred[w] = wm;
  __syncthreads();
  float m = fmaxf(fmaxf(sred[0],sred[1]), fmaxf(sred[2],sred[3]));
  float lsum = 0.f;
  for(int j=tid;j<SEQ_;j+=256){
    float e = expf(p[j]-m);
    p[j] = e; lsum += e;
  }
  float wsumv = wave_rsum(lsum);
  if(lane==0) sred[4+w] = wsumv;
  __syncthreads();
  float inv = 1.0f/(sred[4]+sred[5]+sred[6]+sred[7]);
  int d = tid & (DH_-1);
  int part = tid >> 6;
  const float* vbase = v + (size_t)b*SEQ_*E_ + h*DH_ + d;
  float acc = 0.f;
  for(int j=part;j<SEQ_;j+=4) acc += p[j]*vbase[(size_t)j*E_];
  ored[part][d] = acc;
  __syncthreads();
  if(tid < DH_){
    float sv = (ored[0][tid]+ored[1][tid]+ored[2][tid]+ored[3][tid]) * inv;
    outp[((size_t)(b*SEQ_+row))*E_ + h*DH_ + tid] = sv;
  }
}

// row-wise layernorm over E=512, 256 threads, 2 elems/thread
__global__ void ln_kernel(const float* __restrict__ in, const float* __restrict__ g,
                          const float* __restrict__ bb, float* __restrict__ outp){
  int row = blockIdx.x;
  const float* xr = in + (size_t)row*E_;
  float* orow = outp + (size_t)row*E_;
  int tid = threadIdx.x;
  float x0 = xr[tid], x1 = xr[tid+256];
  float s = x0+x1, s2 = x0*x0 + x1*x1;
  float ws1 = wave_rsum(s);
  float ws2 = wave_rsum(s2);
  __shared__ float r1[4], r2[4];
  int w = tid>>6, lane = tid&63;
  if(lane==0){ r1[w]=ws1; r2[w]=ws2; }
  __syncthreads();
  float S  = r1[0]+r1[1]+r1[2]+r1[3];
  float S2 = r2[0]+r2[1]+r2[2]+r2[3];
  float mean = S*(1.0f/E_);
  float var  = S2*(1.0f/E_) - mean*mean;
  float inv = rsqrtf(var + 1e-5f);
  orow[tid]     = (x0-mean)*inv*g[tid]     + bb[tid];
  orow[tid+256] = (x1-mean)*inv*g[tid+256] + bb[tid+256];
}

// out[b,:] = x_flat[b,:] @ Wm + bm  -- two-stage deterministic reduce
__global__ void final_partial(const float* __restrict__ x, const float* __restrict__ Wm,
                              float* __restrict__ part){
  int b  = blockIdx.x >> 7;
  int ch = blockIdx.x & 127;
  const float* xb = x + (size_t)b*SEQ_*E_;
  int k0 = ch*4096;
  float acc[NC_] = {};
  for(int k=k0+threadIdx.x; k<k0+4096; k+=256){
    float xv = xb[k];
    const float* wrow = Wm + (size_t)k*NC_;
#pragma unroll
    for(int c=0;c<NC_;++c) acc[c] += xv*wrow[c];
  }
#pragma unroll
  for(int c=0;c<NC_;++c) acc[c] = wave_rsum(acc[c]);
  __shared__ float r[4][NC_];
  int w = threadIdx.x>>6, lane = threadIdx.x&63;
  if(lane==0){
#pragma unroll
    for(int c=0;c<NC_;++c) r[w][c] = acc[c];
  }
  __syncthreads();
  if(threadIdx.x==0){
#pragma unroll
    for(int c=0;c<NC_;++c)
      part[(size_t)blockIdx.x*NC_ + c] = r[0][c]+r[1][c]+r[2][c]+r[3][c];
  }
}

__global__ void final_reduce(const float* __restrict__ part, const float* __restrict__ bm,
                             float* __restrict__ out){
  int t = threadIdx.x;
  if(t >= B_*NC_) return;
  int b = t / NC_, c = t % NC_;
  float s = bm[c];
  for(int i=0;i<128;++i) s += part[(size_t)(b*128+i)*NC_ + c];
  out[t] = s;
}

extern "C" void kernel_launch(void* const* d_in, const int* in_sizes, int n_in,
                              void* d_out, int out_size, void* d_ws, size_t ws_size,
                              hipStream_t stream){
  const int*   inp   = (const int*)d_in[0];
  const float* emb   = (const float*)d_in[1];
  const float* gamma = (const float*)d_in[2];
  const float* beta  = (const float*)d_in[3];
  const float* Wq    = (const float*)d_in[4];
  const float* bq    = (const float*)d_in[5];
  const float* Wv    = (const float*)d_in[6];
  const float* bv    = (const float*)d_in[7];
  const float* hyper = (const float*)d_in[8];
  const float* W1    = (const float*)d_in[9];
  const float* b1    = (const float*)d_in[10];
  const float* W2    = (const float*)d_in[11];
  const float* b2    = (const float*)d_in[12];
  const float* Wm    = (const float*)d_in[13];
  const float* bm    = (const float*)d_in[14];
  float* out = (float*)d_out;

  char* ws = (char*)d_ws;
  size_t off = 0;
  auto alloc = [&](size_t bytes)->void*{
    void* p = ws + off; off += (bytes + 255) & ~(size_t)255; return p;
  };
  const size_t NTOK = (size_t)B_*SEQ_;
  float* X  = (float*)alloc(NTOK*E_*sizeof(float));
  float* Q  = (float*)alloc(NTOK*E_*sizeof(float));
  float* V  = (float*)alloc(NTOK*E_*sizeof(float));
  float* A  = (float*)alloc(NTOK*E_*sizeof(float));
  float* Hh = (float*)alloc(NTOK*HID_*sizeof(float));
  int*   Bk = (int*)  alloc((size_t)B_*H_*SEQ_*sizeof(int));
  float* Pp = (float*)alloc((size_t)B_*128*NC_*sizeof(float));
  (void)ws_size; (void)in_sizes; (void)n_in; (void)out_size;

  embed_pe_kernel<<<B_*SEQ_, 256, 0, stream>>>(inp, emb, X);

  dim3 gQV(E_/64,  (B_*SEQ_)/64);
  dim3 gF1(HID_/64,(B_*SEQ_)/64);
  for(int l=0;l<ENC_;++l){
    gemm_f32<0><<<gQV, 256, 0, stream>>>(X, Wq, bq, nullptr, Q, B_*SEQ_, E_, E_);
    gemm_f32<0><<<gQV, 256, 0, stream>>>(X, Wv, bv, nullptr, V, B_*SEQ_, E_, E_);
    bucket_kernel<<<(B_*SEQ_*H_)/256, 256, 0, stream>>>(Q, hyper, Bk);
    attn_kernel<<<B_*H_*SEQ_, 256, 0, stream>>>(Q, V, Bk, A);
    ln_kernel<<<B_*SEQ_, 256, 0, stream>>>(A, gamma, beta, X);
    gemm_f32<1><<<gF1, 256, 0, stream>>>(X, W1, b1, nullptr, Hh, B_*SEQ_, HID_, E_);
    gemm_f32<2><<<gQV, 256, 0, stream>>>(Hh, W2, b2, X, A, B_*SEQ_, E_, HID_);
    ln_kernel<<<B_*SEQ_, 256, 0, stream>>>(A, gamma, beta, X);
  }
  final_partial<<<B_*128, 256, 0, stream>>>(X, Wm, Pp);
  final_reduce<<<1, 32, 0, stream>>>(Pp, bm, out);
}

// Round 2
// 2961.412 us; speedup vs baseline: 5.1341x; 5.1341x over previous
//
#include <hip/hip_runtime.h>
#include <hip/hip_bf16.h>
#include <math.h>

#define B_    4
#define SEQ_  1024
#define E_    512
#define H_    8
#define DH_   64
#define NHYP_ 6
#define HID_  2048
#define NC_   6
#define ENC_  6
#define BH_   (B_*H_)

typedef __attribute__((ext_vector_type(8))) short short8;
typedef __attribute__((ext_vector_type(4))) float f32x4;

static __device__ __forceinline__ float wave_rsum(float v){
#pragma unroll
  for(int o=32;o;o>>=1) v += __shfl_down(v,o,64);
  return v;
}

// x[b,s,:] = emb[idx[b,s],:] + pos_encoding(s,:)
__global__ void embed_pe_kernel(const int* __restrict__ inp, const float* __restrict__ emb,
                                float* __restrict__ x){
  int row = blockIdx.x;            // b*SEQ + s
  int s = row & (SEQ_-1);
  int idx = inp[row];
  const float* er = emb + (size_t)idx*E_;
  float* xr = x + (size_t)row*E_;
  for(int c=threadIdx.x;c<E_;c+=blockDim.x){
    int i = c>>1;
    float div = expf(-(float)i * 0.0359778920780319646f);
    float ang = (float)s * div;
    float pe = (c&1) ? cosf(ang) : sinf(ang);
    xr[c] = er[c] + pe;
  }
}

// C[M,N] = A[M,K]@B[K,N] + bias, EPI: 0=bias, 1=bias+relu, 2=bias+residual
template<int EPI>
__global__ void gemm_f32(const float* __restrict__ A, const float* __restrict__ Bm,
                         const float* __restrict__ bias, const float* __restrict__ res,
                         float* __restrict__ C, int M, int N, int K){
  __shared__ float As[16][65];   // As[k][m]
  __shared__ float Bs[16][65];   // Bs[k][n]
  int tid = threadIdx.x;
  int tx = tid & 15, ty = tid >> 4;
  int bn = blockIdx.x * 64, bm = blockIdx.y * 64;
  float acc[4][4] = {};
  for(int k0=0;k0<K;k0+=16){
    {
      int kk = tid & 15, m = tid >> 4;
#pragma unroll
      for(int p=0;p<4;++p)
        As[kk][m + p*16] = A[(size_t)(bm + m + p*16)*K + k0 + kk];
      int n = tid & 63, k2 = tid >> 6;
#pragma unroll
      for(int p=0;p<4;++p)
        Bs[k2 + p*4][n] = Bm[(size_t)(k0 + k2 + p*4)*N + bn + n];
    }
    __syncthreads();
#pragma unroll
    for(int kk=0;kk<16;++kk){
      float a[4], bv[4];
#pragma unroll
      for(int i=0;i<4;++i) a[i] = As[kk][ty + 16*i];
#pragma unroll
      for(int j=0;j<4;++j) bv[j] = Bs[kk][tx + 16*j];
#pragma unroll
      for(int i=0;i<4;++i)
#pragma unroll
        for(int j=0;j<4;++j) acc[i][j] += a[i]*bv[j];
    }
    __syncthreads();
  }
#pragma unroll
  for(int i=0;i<4;++i){
    int r = bm + ty + 16*i;
#pragma unroll
    for(int j=0;j<4;++j){
      int c = bn + tx + 16*j;
      float vv = acc[i][j] + bias[c];
      if(EPI==1) vv = fmaxf(vv, 0.0f);
      if(EPI==2) vv += res[(size_t)r*N + c];
      C[(size_t)r*N + c] = vv;
    }
  }
}

// buckets from FP32 q so bucket decisions match the reference bit-for-bit-ish
__global__ void bucket_kernel(const float* __restrict__ q, const float* __restrict__ hyper,
                              int* __restrict__ buckets){
  int t = blockIdx.x*256 + threadIdx.x;
  if(t >= B_*SEQ_*H_) return;
  int h = t & (H_-1);
  int n = (t >> 3) & (SEQ_-1);
  int b = t >> 13;
  const float* qr = q + ((size_t)(b*SEQ_ + n))*E_ + h*DH_;
  float pr[NHYP_];
#pragma unroll
  for(int y=0;y<NHYP_;++y) pr[y] = hyper[DH_*NHYP_ + y];   // bias-1 row
  for(int d=0;d<DH_;++d){
    float qd = qr[d];
#pragma unroll
    for(int y=0;y<NHYP_;++y) pr[y] += qd * hyper[d*NHYP_ + y];
  }
  int bk = 0;
#pragma unroll
  for(int y=0;y<NHYP_;++y) bk |= (pr[y] >= 0.0f) ? (1<<y) : 0;
  buckets[(b*H_ + h)*SEQ_ + n] = bk;
}

// fp32 Q,V [B,SEQ,E] -> bf16 Qh[bh][n][64] and transposed Vt[bh][d][n]
__global__ __launch_bounds__(256) void repack_kernel(
    const float* __restrict__ Q, const float* __restrict__ V,
    ushort* __restrict__ Qh, ushort* __restrict__ Vt){
  int nt = blockIdx.x & 15;
  int bh = blockIdx.x >> 4;
  int b = bh >> 3, h = bh & 7;
  int n0 = nt*64;
  __shared__ ushort T[64][72];      // T[d][n]
  int tid = threadIdx.x;
  int r = tid >> 2, cseg = (tid & 3) * 16;
  const float* qrow = Q + ((size_t)(b*SEQ_) + n0 + r)*E_ + h*DH_ + cseg;
  const float* vrow = V + ((size_t)(b*SEQ_) + n0 + r)*E_ + h*DH_ + cseg;
  __attribute__((aligned(16))) ushort qb[16];
#pragma unroll
  for(int j=0;j<16;++j){
    __hip_bfloat16 hq = __float2bfloat16(qrow[j]);
    qb[j] = *(ushort*)&hq;
    __hip_bfloat16 hv = __float2bfloat16(vrow[j]);
    T[cseg + j][r] = *(ushort*)&hv;
  }
  ushort* qdst = Qh + ((size_t)bh*SEQ_ + n0 + r)*DH_ + cseg;
  *(uint4*)&qdst[0] = *(uint4*)&qb[0];
  *(uint4*)&qdst[8] = *(uint4*)&qb[8];
  __syncthreads();
  // write Vt rows (d-major, keys contiguous)
  int d = tid >> 2, nseg = (tid & 3) * 16;
  ushort* vdst = Vt + ((size_t)bh*DH_ + d)*SEQ_ + n0 + nseg;
  *(uint4*)&vdst[0] = *(uint4*)&T[d][nseg];
  *(uint4*)&vdst[8] = *(uint4*)&T[d][nseg+8];
}

// flash attention, MFMA bf16. Block: 4 waves, 64 q-rows of one (b,h).
__global__ __launch_bounds__(256) void attn_mfma_kernel(
    const ushort* __restrict__ Qh,   // [BH][SEQ][64]
    const ushort* __restrict__ Vt,   // [BH][64][SEQ]
    const int* __restrict__ buckets, // [BH][SEQ]
    float* __restrict__ outp)        // [B][SEQ][E]
{
  int qt = blockIdx.x & 15;
  int bh = blockIdx.x >> 4;
  int b = bh >> 3, h = bh & 7;
  int tid = threadIdx.x;
  int w = tid >> 6, lane = tid & 63;
  int g = lane >> 4, li = lane & 15;

  __shared__ ushort Qs[64][72];
  __shared__ ushort Ks[64][72];
  __shared__ ushort Vs[64][72];   // Vs[d][key]
  __shared__ ushort Ps[64][72];
  __shared__ int bqs[64];
  __shared__ int bks[64];

  const ushort* Qbase = Qh + (size_t)bh*SEQ_*DH_;
  const ushort* Vbase = Vt + (size_t)bh*DH_*SEQ_;
  const int* Bb = buckets + bh*SEQ_;
  int q0 = qt*64;

  // stage Q tile + q buckets
#pragma unroll
  for(int it=0; it<2; ++it){
    int t2 = tid + it*256;
    int r = t2 >> 3, c = t2 & 7;
    *(uint4*)&Qs[r][c*8] = *(const uint4*)&Qbase[(size_t)(q0 + r)*DH_ + c*8];
  }
  if(tid < 64) bqs[tid] = Bb[q0 + tid];
  __syncthreads();

  short8 qa[2];
#pragma unroll
  for(int kc=0; kc<2; ++kc)
    qa[kc] = *(short8*)&Qs[w*16 + li][kc*32 + g*8];

  f32x4 acc_o[4] = {};
  float mrow[4], lrow[4];
#pragma unroll
  for(int i=0;i<4;++i){ mrow[i] = -1e30f; lrow[i] = 0.f; }

  const float invsq = 0.04419417382415922f;  // 1/sqrt(512)

  for(int kt=0; kt<16; ++kt){
    int j0 = kt*64;
    __syncthreads();   // previous iteration's LDS reads done
#pragma unroll
    for(int it=0; it<2; ++it){
      int t2 = tid + it*256;
      int r = t2 >> 3, c = t2 & 7;
      *(uint4*)&Ks[r][c*8] = *(const uint4*)&Qbase[(size_t)(j0 + r)*DH_ + c*8];
      *(uint4*)&Vs[r][c*8] = *(const uint4*)&Vbase[(size_t)r*SEQ_ + j0 + c*8];
    }
    if(tid < 64) bks[tid] = Bb[j0 + tid];
    __syncthreads();

    // S = Q K^T  (gemm_bt pattern: B^T rows are K-tile rows)
    f32x4 accs[4];
#pragma unroll
    for(int nt=0; nt<4; ++nt){
      f32x4 z = {};
#pragma unroll
      for(int kc=0; kc<2; ++kc){
        short8 kb = *(short8*)&Ks[nt*16 + li][kc*32 + g*8];
        z = __builtin_amdgcn_mfma_f32_16x16x32_bf16(qa[kc], kb, z, 0,0,0);
      }
      accs[nt] = z;
    }
    // per-lane key buckets for the 4 column tiles
    int bkc[4];
#pragma unroll
    for(int nt=0;nt<4;++nt) bkc[nt] = bks[nt*16 + li];

    float p[4][4];
#pragma unroll
    for(int i=0;i<4;++i){
      int rloc = w*16 + g*4 + i;
      int bq = bqs[rloc];
      float rmax = -1e30f;
#pragma unroll
      for(int nt=0;nt<4;++nt){
        float cnt = (bkc[nt] == bq) ? 63.f : 62.f;
        float lg = accs[nt][i] * (invsq * cnt);
        p[nt][i] = lg;
        rmax = fmaxf(rmax, lg);
      }
#pragma unroll
      for(int o=8;o;o>>=1) rmax = fmaxf(rmax, __shfl_xor(rmax, o, 64));
      float mnew = fmaxf(mrow[i], rmax);
      float scale = __expf(mrow[i] - mnew);
      mrow[i] = mnew;
      float rs = 0.f;
#pragma unroll
      for(int nt=0;nt<4;++nt){
        float e = __expf(p[nt][i] - mnew);
        p[nt][i] = e;
        rs += e;
      }
#pragma unroll
      for(int o=8;o;o>>=1) rs += __shfl_xor(rs, o, 64);
      lrow[i] = lrow[i]*scale + rs;
#pragma unroll
      for(int dt=0;dt<4;++dt) acc_o[dt][i] *= scale;
    }
    // P -> LDS (wave-private rows; no cross-wave dependency)
#pragma unroll
    for(int i=0;i<4;++i){
      int rloc = w*16 + g*4 + i;
#pragma unroll
      for(int nt=0;nt<4;++nt){
        __hip_bfloat16 hb = __float2bfloat16(p[nt][i]);
        Ps[rloc][nt*16 + li] = *(ushort*)&hb;
      }
    }
    // O += P @ V   (B^T rows are Vs[d][key] rows)
#pragma unroll
    for(int dt=0; dt<4; ++dt){
      f32x4 z = acc_o[dt];
#pragma unroll
      for(int kc=0; kc<2; ++kc){
        short8 pa = *(short8*)&Ps[w*16 + li][kc*32 + g*8];
        short8 vb = *(short8*)&Vs[dt*16 + li][kc*32 + g*8];
        z = __builtin_amdgcn_mfma_f32_16x16x32_bf16(pa, vb, z, 0,0,0);
      }
      acc_o[dt] = z;
    }
  }
  // epilogue: divide by row sums, store fp32
  float* obase = outp + ((size_t)(b*SEQ_ + q0 + w*16 + g*4))*E_ + h*DH_;
#pragma unroll
  for(int i=0;i<4;++i){
    float inv = 1.0f / lrow[i];
#pragma unroll
    for(int dt=0;dt<4;++dt)
      obase[(size_t)i*E_ + dt*16 + li] = acc_o[dt][i] * inv;
  }
}

// row-wise layernorm over E=512
__global__ void ln_kernel(const float* __restrict__ in, const float* __restrict__ g,
                          const float* __restrict__ bb, float* __restrict__ outp){
  int row = blockIdx.x;
  const float* xr = in + (size_t)row*E_;
  float* orow = outp + (size_t)row*E_;
  int tid = threadIdx.x;
  float x0 = xr[tid], x1 = xr[tid+256];
  float s = x0+x1, s2 = x0*x0 + x1*x1;
  float ws1 = wave_rsum(s);
  float ws2 = wave_rsum(s2);
  __shared__ float r1[4], r2[4];
  int w = tid>>6, lane = tid&63;
  if(lane==0){ r1[w]=ws1; r2[w]=ws2; }
  __syncthreads();
  float S  = r1[0]+r1[1]+r1[2]+r1[3];
  float S2 = r2[0]+r2[1]+r2[2]+r2[3];
  float mean = S*(1.0f/E_);
  float var  = S2*(1.0f/E_) - mean*mean;
  float inv = rsqrtf(var + 1e-5f);
  orow[tid]     = (x0-mean)*inv*g[tid]     + bb[tid];
  orow[tid+256] = (x1-mean)*inv*g[tid+256] + bb[tid+256];
}

__global__ void final_partial(const float* __restrict__ x, const float* __restrict__ Wm,
                              float* __restrict__ part){
  int b  = blockIdx.x >> 7;
  int ch = blockIdx.x & 127;
  const float* xb = x + (size_t)b*SEQ_*E_;
  int k0 = ch*4096;
  float acc[NC_] = {};
  for(int k=k0+threadIdx.x; k<k0+4096; k+=256){
    float xv = xb[k];
    const float* wrow = Wm + (size_t)k*NC_;
#pragma unroll
    for(int c=0;c<NC_;++c) acc[c] += xv*wrow[c];
  }
#pragma unroll
  for(int c=0;c<NC_;++c) acc[c] = wave_rsum(acc[c]);
  __shared__ float r[4][NC_];
  int w = threadIdx.x>>6, lane = threadIdx.x&63;
  if(lane==0){
#pragma unroll
    for(int c=0;c<NC_;++c) r[w][c] = acc[c];
  }
  __syncthreads();
  if(threadIdx.x==0){
#pragma unroll
    for(int c=0;c<NC_;++c)
      part[(size_t)blockIdx.x*NC_ + c] = r[0][c]+r[1][c]+r[2][c]+r[3][c];
  }
}

__global__ void final_reduce(const float* __restrict__ part, const float* __restrict__ bm,
                             float* __restrict__ out){
  int t = threadIdx.x;
  if(t >= B_*NC_) return;
  int b = t / NC_, c = t % NC_;
  float s = bm[c];
  for(int i=0;i<128;++i) s += part[(size_t)(b*128+i)*NC_ + c];
  out[t] = s;
}

extern "C" void kernel_launch(void* const* d_in, const int* in_sizes, int n_in,
                              void* d_out, int out_size, void* d_ws, size_t ws_size,
                              hipStream_t stream){
  const int*   inp   = (const int*)d_in[0];
  const float* emb   = (const float*)d_in[1];
  const float* gamma = (const float*)d_in[2];
  const float* beta  = (const float*)d_in[3];
  const float* Wq    = (const float*)d_in[4];
  const float* bq    = (const float*)d_in[5];
  const float* Wv    = (const float*)d_in[6];
  const float* bv    = (const float*)d_in[7];
  const float* hyper = (const float*)d_in[8];
  const float* W1    = (const float*)d_in[9];
  const float* b1    = (const float*)d_in[10];
  const float* W2    = (const float*)d_in[11];
  const float* b2    = (const float*)d_in[12];
  const float* Wm    = (const float*)d_in[13];
  const float* bm    = (const float*)d_in[14];
  float* out = (float*)d_out;

  char* ws = (char*)d_ws;
  size_t off = 0;
  auto alloc = [&](size_t bytes)->void*{
    void* p = ws + off; off += (bytes + 255) & ~(size_t)255; return p;
  };
  const size_t NTOK = (size_t)B_*SEQ_;
  float*  X  = (float*)alloc(NTOK*E_*sizeof(float));
  float*  Q  = (float*)alloc(NTOK*E_*sizeof(float));
  float*  V  = (float*)alloc(NTOK*E_*sizeof(float));
  float*  A  = (float*)alloc(NTOK*E_*sizeof(float));
  float*  Hh = (float*)alloc(NTOK*HID_*sizeof(float));
  int*    Bk = (int*)  alloc((size_t)BH_*SEQ_*sizeof(int));
  float*  Pp = (float*)alloc((size_t)B_*128*NC_*sizeof(float));
  ushort* Qh = (ushort*)alloc((size_t)BH_*SEQ_*DH_*sizeof(ushort));
  ushort* Vt = (ushort*)alloc((size_t)BH_*DH_*SEQ_*sizeof(ushort));
  (void)ws_size; (void)in_sizes; (void)n_in; (void)out_size;

  embed_pe_kernel<<<B_*SEQ_, 256, 0, stream>>>(inp, emb, X);

  dim3 gQV(E_/64,  (B_*SEQ_)/64);
  dim3 gF1(HID_/64,(B_*SEQ_)/64);
  for(int l=0;l<ENC_;++l){
    gemm_f32<0><<<gQV, 256, 0, stream>>>(X, Wq, bq, nullptr, Q, B_*SEQ_, E_, E_);
    gemm_f32<0><<<gQV, 256, 0, stream>>>(X, Wv, bv, nullptr, V, B_*SEQ_, E_, E_);
    bucket_kernel<<<(B_*SEQ_*H_)/256, 256, 0, stream>>>(Q, hyper, Bk);
    repack_kernel<<<BH_*16, 256, 0, stream>>>(Q, V, Qh, Vt);
    attn_mfma_kernel<<<BH_*16, 256, 0, stream>>>(Qh, Vt, Bk, A);
    ln_kernel<<<B_*SEQ_, 256, 0, stream>>>(A, gamma, beta, X);
    gemm_f32<1><<<gF1, 256, 0, stream>>>(X, W1, b1, nullptr, Hh, B_*SEQ_, HID_, E_);
    gemm_f32<2><<<gQV, 256, 0, stream>>>(Hh, W2, b2, X, A, B_*SEQ_, E_, HID_);
    ln_kernel<<<B_*SEQ_, 256, 0, stream>>>(A, gamma, beta, X);
  }
  final_partial<<<B_*128, 256, 0, stream>>>(X, Wm, Pp);
  final_reduce<<<1, 32, 0, stream>>>(Pp, bm, out);
}

// Round 3
// 907.997 us; speedup vs baseline: 16.7448x; 3.2615x over previous
//
#include <hip/hip_runtime.h>
#include <hip/hip_bf16.h>
#include <math.h>

#define B_    4
#define SEQ_  1024
#define E_    512
#define H_    8
#define DH_   64
#define NHYP_ 6
#define HID_  2048
#define NC_   6
#define ENC_  6
#define BH_   (B_*H_)

typedef __attribute__((ext_vector_type(8))) short short8;
typedef __attribute__((ext_vector_type(4))) float f32x4;

static __device__ __forceinline__ float wave_rsum(float v){
#pragma unroll
  for(int o=32;o;o>>=1) v += __shfl_down(v,o,64);
  return v;
}
static __device__ __forceinline__ ushort f2b(float v){
  __hip_bfloat16 h = __float2bfloat16(v);
  return *(ushort*)&h;
}

// x[b,s,:] = emb[idx[b,s],:] + pos_encoding(s,:)   (also emits bf16 copy)
__global__ void embed_pe_kernel(const int* __restrict__ inp, const float* __restrict__ emb,
                                float* __restrict__ x, ushort* __restrict__ xh){
  int row = blockIdx.x;            // b*SEQ + s
  int s = row & (SEQ_-1);
  int idx = inp[row];
  const float* er = emb + (size_t)idx*E_;
  float* xr = x + (size_t)row*E_;
  ushort* hr = xh + (size_t)row*E_;
  for(int c=threadIdx.x;c<E_;c+=blockDim.x){
    int i = c>>1;
    float div = expf(-(float)i * 0.0359778920780319646f);
    float ang = (float)s * div;
    float pe = (c&1) ? cosf(ang) : sinf(ang);
    float v = er[c] + pe;
    xr[c] = v;
    hr[c] = f2b(v);
  }
}

// one-time: W[K][N] fp32 -> Wt[N][K] bf16
__global__ __launch_bounds__(256) void transpose_cast(
    const float* __restrict__ W, ushort* __restrict__ Wt, int K, int N){
  __shared__ float T[32][33];
  int tx = threadIdx.x & 31, ty = threadIdx.x >> 5;   // 32x8
  int n0 = blockIdx.x*32, k0 = blockIdx.y*32;
#pragma unroll
  for(int i=0;i<32;i+=8) T[ty+i][tx] = W[(size_t)(k0+ty+i)*N + n0+tx];
  __syncthreads();
#pragma unroll
  for(int i=0;i<32;i+=8)
    Wt[(size_t)(n0+ty+i)*K + k0+tx] = f2b(T[tx][ty+i]);
}

// C[M,N] = A[M,K](bf16) @ Bt[N,K]^T(bf16) + bias
// EPI 0: fp32 out;  1: relu -> bf16 out;  2: +res -> fp32 out
template<int BM, int EPI>
__global__ __launch_bounds__(256) void gemm_mfma(
    const ushort* __restrict__ A, const ushort* __restrict__ Bt,
    const float* __restrict__ bias, const float* __restrict__ res,
    void* __restrict__ Cout, int M, int N, int K)
{
  constexpr int BN  = 128;
  constexpr int MI  = BM/32;        // 16x16 frags per wave (M dir)
  constexpr int NI  = 4;            // wave-tile 64 cols
  constexpr int LDA = 40;           // padded bf16 row stride (80B, 16B-aligned frags)
  __shared__ ushort As[BM*LDA];
  __shared__ ushort Bs[BN*LDA];
  int tid = threadIdx.x;
  int w = tid>>6, lane = tid&63, g = lane>>4, li = lane&15;
  int wr = w>>1, wc = w&1;
  int bm = blockIdx.y*BM, bn = blockIdx.x*BN;

  f32x4 acc[MI][NI] = {};

  for(int k0=0;k0<K;k0+=32){
    __syncthreads();
#pragma unroll
    for(int it=0; it<BM/64; ++it){
      int c = tid + it*256; int r = c>>2, kq = (c&3)*8;
      *(uint4*)&As[r*LDA+kq] = *(const uint4*)&A[(size_t)(bm+r)*K + k0 + kq];
    }
#pragma unroll
    for(int it=0; it<2; ++it){
      int c = tid + it*256; int r = c>>2, kq = (c&3)*8;
      *(uint4*)&Bs[r*LDA+kq] = *(const uint4*)&Bt[(size_t)(bn+r)*K + k0 + kq];
    }
    __syncthreads();
    short8 af[MI], bf[NI];
#pragma unroll
    for(int mi=0;mi<MI;++mi) af[mi] = *(short8*)&As[(wr*(BM/2)+mi*16+li)*LDA + g*8];
#pragma unroll
    for(int ni=0;ni<NI;++ni) bf[ni] = *(short8*)&Bs[(wc*64+ni*16+li)*LDA + g*8];
#pragma unroll
    for(int mi=0;mi<MI;++mi)
#pragma unroll
      for(int ni=0;ni<NI;++ni)
        acc[mi][ni] = __builtin_amdgcn_mfma_f32_16x16x32_bf16(af[mi], bf[ni], acc[mi][ni], 0,0,0);
  }

#pragma unroll
  for(int mi=0;mi<MI;++mi){
    int rbase = bm + wr*(BM/2) + mi*16 + g*4;
#pragma unroll
    for(int j=0;j<4;++j){
      int r = rbase + j;
#pragma unroll
      for(int ni=0;ni<NI;++ni){
        int cc = bn + wc*64 + ni*16 + li;
        float vv = acc[mi][ni][j] + bias[cc];
        if(EPI==1){
          vv = fmaxf(vv, 0.0f);
          ((ushort*)Cout)[(size_t)r*N + cc] = f2b(vv);
        } else if(EPI==2){
          vv += res[(size_t)r*N + cc];
          ((float*)Cout)[(size_t)r*N + cc] = vv;
        } else {
          ((float*)Cout)[(size_t)r*N + cc] = vv;
        }
      }
    }
  }
}

// buckets from FP32 q
__global__ void bucket_kernel(const float* __restrict__ q, const float* __restrict__ hyper,
                              int* __restrict__ buckets){
  int t = blockIdx.x*256 + threadIdx.x;
  if(t >= B_*SEQ_*H_) return;
  int h = t & (H_-1);
  int n = (t >> 3) & (SEQ_-1);
  int b = t >> 13;
  const float* qr = q + ((size_t)(b*SEQ_ + n))*E_ + h*DH_;
  float pr[NHYP_];
#pragma unroll
  for(int y=0;y<NHYP_;++y) pr[y] = hyper[DH_*NHYP_ + y];
  for(int d=0;d<DH_;++d){
    float qd = qr[d];
#pragma unroll
    for(int y=0;y<NHYP_;++y) pr[y] += qd * hyper[d*NHYP_ + y];
  }
  int bk = 0;
#pragma unroll
  for(int y=0;y<NHYP_;++y) bk |= (pr[y] >= 0.0f) ? (1<<y) : 0;
  buckets[(b*H_ + h)*SEQ_ + n] = bk;
}

// fp32 Q,V [B,SEQ,E] -> bf16 Qh[bh][n][64] and transposed Vt[bh][d][n]
__global__ __launch_bounds__(256) void repack_kernel(
    const float* __restrict__ Q, const float* __restrict__ V,
    ushort* __restrict__ Qh, ushort* __restrict__ Vt){
  int nt = blockIdx.x & 15;
  int bh = blockIdx.x >> 4;
  int b = bh >> 3, h = bh & 7;
  int n0 = nt*64;
  __shared__ ushort T[64][72];
  int tid = threadIdx.x;
  int r = tid >> 2, cseg = (tid & 3) * 16;
  const float* qrow = Q + ((size_t)(b*SEQ_) + n0 + r)*E_ + h*DH_ + cseg;
  const float* vrow = V + ((size_t)(b*SEQ_) + n0 + r)*E_ + h*DH_ + cseg;
  __attribute__((aligned(16))) ushort qb[16];
#pragma unroll
  for(int j=0;j<16;++j){
    qb[j] = f2b(qrow[j]);
    T[cseg + j][r] = f2b(vrow[j]);
  }
  ushort* qdst = Qh + ((size_t)bh*SEQ_ + n0 + r)*DH_ + cseg;
  *(uint4*)&qdst[0] = *(uint4*)&qb[0];
  *(uint4*)&qdst[8] = *(uint4*)&qb[8];
  __syncthreads();
  int d = tid >> 2, nseg = (tid & 3) * 16;
  ushort* vdst = Vt + ((size_t)bh*DH_ + d)*SEQ_ + n0 + nseg;
  *(uint4*)&vdst[0] = *(uint4*)&T[d][nseg];
  *(uint4*)&vdst[8] = *(uint4*)&T[d][nseg+8];
}

// flash attention, MFMA bf16. Block: 4 waves, 64 q-rows of one (b,h).
__global__ __launch_bounds__(256) void attn_mfma_kernel(
    const ushort* __restrict__ Qh,   // [BH][SEQ][64]
    const ushort* __restrict__ Vt,   // [BH][64][SEQ]
    const int* __restrict__ buckets, // [BH][SEQ]
    float* __restrict__ outp)        // [B][SEQ][E]
{
  int qt = blockIdx.x & 15;
  int bh = blockIdx.x >> 4;
  int b = bh >> 3, h = bh & 7;
  int tid = threadIdx.x;
  int w = tid >> 6, lane = tid & 63;
  int g = lane >> 4, li = lane & 15;

  __shared__ ushort Qs[64][72];
  __shared__ ushort Ks[64][72];
  __shared__ ushort Vs[64][72];
  __shared__ ushort Ps[64][72];
  __shared__ int bqs[64];
  __shared__ int bks[64];

  const ushort* Qbase = Qh + (size_t)bh*SEQ_*DH_;
  const ushort* Vbase = Vt + (size_t)bh*DH_*SEQ_;
  const int* Bb = buckets + bh*SEQ_;
  int q0 = qt*64;

#pragma unroll
  for(int it=0; it<2; ++it){
    int t2 = tid + it*256;
    int r = t2 >> 3, c = t2 & 7;
    *(uint4*)&Qs[r][c*8] = *(const uint4*)&Qbase[(size_t)(q0 + r)*DH_ + c*8];
  }
  if(tid < 64) bqs[tid] = Bb[q0 + tid];
  __syncthreads();

  short8 qa[2];
#pragma unroll
  for(int kc=0; kc<2; ++kc)
    qa[kc] = *(short8*)&Qs[w*16 + li][kc*32 + g*8];

  f32x4 acc_o[4] = {};
  float mrow[4], lrow[4];
#pragma unroll
  for(int i=0;i<4;++i){ mrow[i] = -1e30f; lrow[i] = 0.f; }

  const float invsq = 0.04419417382415922f;  // 1/sqrt(512)

  for(int kt=0; kt<16; ++kt){
    int j0 = kt*64;
    __syncthreads();
#pragma unroll
    for(int it=0; it<2; ++it){
      int t2 = tid + it*256;
      int r = t2 >> 3, c = t2 & 7;
      *(uint4*)&Ks[r][c*8] = *(const uint4*)&Qbase[(size_t)(j0 + r)*DH_ + c*8];
      *(uint4*)&Vs[r][c*8] = *(const uint4*)&Vbase[(size_t)r*SEQ_ + j0 + c*8];
    }
    if(tid < 64) bks[tid] = Bb[j0 + tid];
    __syncthreads();

    f32x4 accs[4];
#pragma unroll
    for(int nt=0; nt<4; ++nt){
      f32x4 z = {};
#pragma unroll
      for(int kc=0; kc<2; ++kc){
        short8 kb = *(short8*)&Ks[nt*16 + li][kc*32 + g*8];
        z = __builtin_amdgcn_mfma_f32_16x16x32_bf16(qa[kc], kb, z, 0,0,0);
      }
      accs[nt] = z;
    }
    int bkc[4];
#pragma unroll
    for(int nt=0;nt<4;++nt) bkc[nt] = bks[nt*16 + li];

    float p[4][4];
#pragma unroll
    for(int i=0;i<4;++i){
      int rloc = w*16 + g*4 + i;
      int bq = bqs[rloc];
      float rmax = -1e30f;
#pragma unroll
      for(int nt=0;nt<4;++nt){
        float cnt = (bkc[nt] == bq) ? 63.f : 62.f;
        float lg = accs[nt][i] * (invsq * cnt);
        p[nt][i] = lg;
        rmax = fmaxf(rmax, lg);
      }
#pragma unroll
      for(int o=8;o;o>>=1) rmax = fmaxf(rmax, __shfl_xor(rmax, o, 64));
      float mnew = fmaxf(mrow[i], rmax);
      float scale = __expf(mrow[i] - mnew);
      mrow[i] = mnew;
      float rs = 0.f;
#pragma unroll
      for(int nt=0;nt<4;++nt){
        float e = __expf(p[nt][i] - mnew);
        p[nt][i] = e;
        rs += e;
      }
#pragma unroll
      for(int o=8;o;o>>=1) rs += __shfl_xor(rs, o, 64);
      lrow[i] = lrow[i]*scale + rs;
#pragma unroll
      for(int dt=0;dt<4;++dt) acc_o[dt][i] *= scale;
    }
#pragma unroll
    for(int i=0;i<4;++i){
      int rloc = w*16 + g*4 + i;
#pragma unroll
      for(int nt=0;nt<4;++nt)
        Ps[rloc][nt*16 + li] = f2b(p[nt][i]);
    }
#pragma unroll
    for(int dt=0; dt<4; ++dt){
      f32x4 z = acc_o[dt];
#pragma unroll
      for(int kc=0; kc<2; ++kc){
        short8 pa = *(short8*)&Ps[w*16 + li][kc*32 + g*8];
        short8 vb = *(short8*)&Vs[dt*16 + li][kc*32 + g*8];
        z = __builtin_amdgcn_mfma_f32_16x16x32_bf16(pa, vb, z, 0,0,0);
      }
      acc_o[dt] = z;
    }
  }
  float* obase = outp + ((size_t)(b*SEQ_ + q0 + w*16 + g*4))*E_ + h*DH_;
#pragma unroll
  for(int i=0;i<4;++i){
    float inv = 1.0f / lrow[i];
#pragma unroll
    for(int dt=0;dt<4;++dt)
      obase[(size_t)i*E_ + dt*16 + li] = acc_o[dt][i] * inv;
  }
}

// layernorm over E=512, emits fp32 + bf16
__global__ void ln_kernel(const float* __restrict__ in, const float* __restrict__ g,
                          const float* __restrict__ bb, float* __restrict__ outp,
                          ushort* __restrict__ oh){
  int row = blockIdx.x;
  const float* xr = in + (size_t)row*E_;
  float* orow = outp + (size_t)row*E_;
  ushort* hrow = oh + (size_t)row*E_;
  int tid = threadIdx.x;
  float x0 = xr[tid], x1 = xr[tid+256];
  float s = x0+x1, s2 = x0*x0 + x1*x1;
  float ws1 = wave_rsum(s);
  float ws2 = wave_rsum(s2);
  __shared__ float r1[4], r2[4];
  int w = tid>>6, lane = tid&63;
  if(lane==0){ r1[w]=ws1; r2[w]=ws2; }
  __syncthreads();
  float S  = r1[0]+r1[1]+r1[2]+r1[3];
  float S2 = r2[0]+r2[1]+r2[2]+r2[3];
  float mean = S*(1.0f/E_);
  float var  = S2*(1.0f/E_) - mean*mean;
  float inv = rsqrtf(var + 1e-5f);
  float y0 = (x0-mean)*inv*g[tid]     + bb[tid];
  float y1 = (x1-mean)*inv*g[tid+256] + bb[tid+256];
  orow[tid]     = y0;  hrow[tid]     = f2b(y0);
  orow[tid+256] = y1;  hrow[tid+256] = f2b(y1);
}

__global__ void final_partial(const float* __restrict__ x, const float* __restrict__ Wm,
                              float* __restrict__ part){
  int b  = blockIdx.x >> 7;
  int ch = blockIdx.x & 127;
  const float* xb = x + (size_t)b*SEQ_*E_;
  int k0 = ch*4096;
  float acc[NC_] = {};
  for(int k=k0+threadIdx.x; k<k0+4096; k+=256){
    float xv = xb[k];
    const float* wrow = Wm + (size_t)k*NC_;
#pragma unroll
    for(int c=0;c<NC_;++c) acc[c] += xv*wrow[c];
  }
#pragma unroll
  for(int c=0;c<NC_;++c) acc[c] = wave_rsum(acc[c]);
  __shared__ float r[4][NC_];
  int w = threadIdx.x>>6, lane = threadIdx.x&63;
  if(lane==0){
#pragma unroll
    for(int c=0;c<NC_;++c) r[w][c] = acc[c];
  }
  __syncthreads();
  if(threadIdx.x==0){
#pragma unroll
    for(int c=0;c<NC_;++c)
      part[(size_t)blockIdx.x*NC_ + c] = r[0][c]+r[1][c]+r[2][c]+r[3][c];
  }
}

__global__ void final_reduce(const float* __restrict__ part, const float* __restrict__ bm,
                             float* __restrict__ out){
  int t = threadIdx.x;
  if(t >= B_*NC_) return;
  int b = t / NC_, c = t % NC_;
  float s = bm[c];
  for(int i=0;i<128;++i) s += part[(size_t)(b*128+i)*NC_ + c];
  out[t] = s;
}

extern "C" void kernel_launch(void* const* d_in, const int* in_sizes, int n_in,
                              void* d_out, int out_size, void* d_ws, size_t ws_size,
                              hipStream_t stream){
  const int*   inp   = (const int*)d_in[0];
  const float* emb   = (const float*)d_in[1];
  const float* gamma = (const float*)d_in[2];
  const float* beta  = (const float*)d_in[3];
  const float* Wq    = (const float*)d_in[4];
  const float* bq    = (const float*)d_in[5];
  const float* Wv    = (const float*)d_in[6];
  const float* bv    = (const float*)d_in[7];
  const float* hyper = (const float*)d_in[8];
  const float* W1    = (const float*)d_in[9];
  const float* b1    = (const float*)d_in[10];
  const float* W2    = (const float*)d_in[11];
  const float* b2    = (const float*)d_in[12];
  const float* Wm    = (const float*)d_in[13];
  const float* bm    = (const float*)d_in[14];
  float* out = (float*)d_out;

  char* ws = (char*)d_ws;
  size_t off = 0;
  auto alloc = [&](size_t bytes)->void*{
    void* p = ws + off; off += (bytes + 255) & ~(size_t)255; return p;
  };
  const size_t NTOK = (size_t)B_*SEQ_;
  float*  X   = (float*)alloc(NTOK*E_*sizeof(float));
  float*  Q   = (float*)alloc(NTOK*E_*sizeof(float));
  float*  V   = (float*)alloc(NTOK*E_*sizeof(float));
  float*  A   = (float*)alloc(NTOK*E_*sizeof(float));
  ushort* Xh  = (ushort*)alloc(NTOK*E_*sizeof(ushort));
  ushort* Hh  = (ushort*)alloc(NTOK*HID_*sizeof(ushort));
  int*    Bk  = (int*)  alloc((size_t)BH_*SEQ_*sizeof(int));
  float*  Pp  = (float*)alloc((size_t)B_*128*NC_*sizeof(float));
  ushort* Qh  = (ushort*)alloc((size_t)BH_*SEQ_*DH_*sizeof(ushort));
  ushort* Vt  = (ushort*)alloc((size_t)BH_*DH_*SEQ_*sizeof(ushort));
  ushort* WqT = (ushort*)alloc((size_t)E_*E_*sizeof(ushort));
  ushort* WvT = (ushort*)alloc((size_t)E_*E_*sizeof(ushort));
  ushort* W1T = (ushort*)alloc((size_t)HID_*E_*sizeof(ushort));
  ushort* W2T = (ushort*)alloc((size_t)E_*HID_*sizeof(ushort));
  (void)ws_size; (void)in_sizes; (void)n_in; (void)out_size;

  // one-time weight prep: W[K][N] -> Wt[N][K] bf16
  transpose_cast<<<dim3(E_/32,  E_/32),  256, 0, stream>>>(Wq, WqT, E_, E_);
  transpose_cast<<<dim3(E_/32,  E_/32),  256, 0, stream>>>(Wv, WvT, E_, E_);
  transpose_cast<<<dim3(HID_/32,E_/32),  256, 0, stream>>>(W1, W1T, E_, HID_);
  transpose_cast<<<dim3(E_/32,  HID_/32),256, 0, stream>>>(W2, W2T, HID_, E_);

  embed_pe_kernel<<<B_*SEQ_, 256, 0, stream>>>(inp, emb, X, Xh);

  dim3 gQV(E_/128,   (B_*SEQ_)/64);    // BM=64
  dim3 gF1(HID_/128, (B_*SEQ_)/128);   // BM=128
  dim3 gF2(E_/128,   (B_*SEQ_)/64);    // BM=64
  for(int l=0;l<ENC_;++l){
    gemm_mfma<64,0><<<gQV, 256, 0, stream>>>(Xh, WqT, bq, nullptr, Q, B_*SEQ_, E_, E_);
    gemm_mfma<64,0><<<gQV, 256, 0, stream>>>(Xh, WvT, bv, nullptr, V, B_*SEQ_, E_, E_);
    bucket_kernel<<<(B_*SEQ_*H_)/256, 256, 0, stream>>>(Q, hyper, Bk);
    repack_kernel<<<BH_*16, 256, 0, stream>>>(Q, V, Qh, Vt);
    attn_mfma_kernel<<<BH_*16, 256, 0, stream>>>(Qh, Vt, Bk, A);
    ln_kernel<<<B_*SEQ_, 256, 0, stream>>>(A, gamma, beta, X, Xh);
    gemm_mfma<128,1><<<gF1, 256, 0, stream>>>(Xh, W1T, b1, nullptr, Hh, B_*SEQ_, HID_, E_);
    gemm_mfma<64,2><<<gF2, 256, 0, stream>>>(Hh, W2T, b2, X, A, B_*SEQ_, E_, HID_);
    ln_kernel<<<B_*SEQ_, 256, 0, stream>>>(A, gamma, beta, X, Xh);
  }
  final_partial<<<B_*128, 256, 0, stream>>>(X, Wm, Pp);
  final_reduce<<<1, 32, 0, stream>>>(Pp, bm, out);
}